// Round 17
// baseline (78.329 us; speedup 1.0000x reference)
//
#include <hip/hip_runtime.h>

#define BATCH 16
#define TOK   4096
#define DIM   768
#define SMAX  128
#define BM    4     // segments (= MLP rows) per block

typedef float f32x4 __attribute__((ext_vector_type(4)));
typedef short s16x8 __attribute__((ext_vector_type(8)));

__device__ __forceinline__ int lower_bound_i(const int* __restrict__ a, int n, int v) {
    int lo = 0, hi = n;
    while (lo < hi) {
        int m = (lo + hi) >> 1;
        if (a[m] < v) lo = m + 1; else hi = m;
    }
    return lo;
}

__device__ __forceinline__ float f4get(const float4& v, int k) {
    switch (k) {
        case 0: return v.x;
        case 1: return v.y;
        case 2: return v.z;
        default: return v.w;
    }
}

__device__ __forceinline__ void f4acc(float4& a, const float4& v) {
    a.x += v.x; a.y += v.y; a.z += v.z; a.w += v.w;
}

// bf16 round-to-nearest-even (prep kernel, off hot path)
__device__ __forceinline__ unsigned short bf16_rne(float f) {
    unsigned int u = __float_as_uint(f);
    u += 0x7FFFu + ((u >> 16) & 1u);
    return (unsigned short)(u >> 16);
}

// pack two f32 -> bf16x2 (round-half-up)
__device__ __forceinline__ unsigned int bf16_pack2(float f0, float f1) {
    unsigned int u0 = __float_as_uint(f0) + 0x8000u;
    unsigned int u1 = __float_as_uint(f1) + 0x8000u;
    return (u0 >> 16) | (u1 & 0xFFFF0000u);
}

// Prep: W1 [768][384] f32 -> W1T [384][768] bf16 (RNE).
__global__ __launch_bounds__(768)
void prep_w1t_kernel(const float* __restrict__ W1, unsigned short* __restrict__ W1T) {
    const int c = blockIdx.x;     // 0..383
    const int k = threadIdx.x;    // 0..767
    W1T[c * 768 + k] = bf16_rne(W1[(size_t)k * 384 + c]);
}

// Kernel 0: precompute span boundaries (independent parallel searches).
__global__ __launch_bounds__(192)
void bounds_kernel(const int* __restrict__ seg, int* __restrict__ bounds) {
    const int b = blockIdx.x;
    const int s = threadIdx.x;
    if (s <= SMAX)
        bounds[b * (SMAX + 1) + s] = lower_bound_i(seg + b * TOK, TOK, s);
}

// Fused kernel, BM=4 / 512 threads / grid 512 (~2-3 blocks/CU, LDS 52.8 KB):
// sibling blocks on a CU overlap phase A (HBM stream) with phase B (MFMA/
// VALU + barriers); finer grid halves the completion tail. Pieces are the
// R14/R16-verified ones scaled to 4 rows: parity-split float4 phase A,
// mfma_f32_16x16x32_bf16 layer1 (8 waves x 3 N-tiles), fp32 k-split layer2/3.
__global__ __launch_bounds__(512)
void fused_kernel(const float* __restrict__ hidden,
                  const int* __restrict__ bounds,
                  const unsigned short* __restrict__ W1T, const float* __restrict__ b1,
                  const float* __restrict__ W2, const float* __restrict__ b2,
                  const float* __restrict__ W3, const float* __restrict__ b3,
                  float* __restrict__ out) {
    __shared__ __align__(16) unsigned int A_bf32[16 * 388]; // 16 rows x 776 bf16 = 24.8 KB
    __shared__ __align__(16) float X1[BM * 384];            //  6 KB
    __shared__ __align__(16) float X2[BM * 128];            //  2 KB
    __shared__ __align__(16) float P2[4 * BM * 128];        //  8 KB
    __shared__ __align__(16) float4 SCR[4 * 64 * 3];        // 12 KB phase-A scratch

    const int tid  = threadIdx.x;
    const int row0 = blockIdx.x * BM;
    const int b    = row0 / SMAX;
    const int s0   = row0 % SMAX;
    const int grp  = tid >> 7;    // segment 0..3
    const int lane = tid & 127;
    const int h    = lane >> 6;   // token-parity half 0/1
    const int l6   = lane & 63;   // owns cols l6*12 .. l6*12+11

    // zero padding rows 4-15 (MFMA A rows; must be 0)
    for (int i = tid; i < 12 * 388; i += 512)
        A_bf32[4 * 388 + i] = 0u;

    // ================= phase A: parity-split segment sums =================
    {
        const int lo = bounds[b * (SMAX + 1) + s0 + grp];
        const int hi = bounds[b * (SMAX + 1) + s0 + grp + 1];

        const float4* __restrict__ hp =
            reinterpret_cast<const float4*>(hidden + (size_t)b * TOK * DIM) + l6 * 3;

        float4 a0 = make_float4(0.f, 0.f, 0.f, 0.f);
        float4 a1 = make_float4(0.f, 0.f, 0.f, 0.f);
        float4 a2 = make_float4(0.f, 0.f, 0.f, 0.f);

        int t = lo + h;
        for (; t + 8 <= hi; t += 8) {
            float4 v0[4], v1[4], v2[4];
            #pragma unroll
            for (int u = 0; u < 4; ++u) {
                const float4* p = hp + (size_t)(t + 2 * u) * 192;
                v0[u] = p[0]; v1[u] = p[1]; v2[u] = p[2];
            }
            #pragma unroll
            for (int u = 0; u < 4; ++u) {
                f4acc(a0, v0[u]); f4acc(a1, v1[u]); f4acc(a2, v2[u]);
            }
        }
        for (; t < hi; t += 2) {
            const float4* p = hp + (size_t)t * 192;
            f4acc(a0, p[0]); f4acc(a1, p[1]); f4acc(a2, p[2]);
        }

        float4* scr = &SCR[(grp * 64 + l6) * 3];
        if (h == 1) {
            scr[0] = a0; scr[1] = a1; scr[2] = a2;
        }
        __syncthreads();
        if (h == 0) {
            f4acc(a0, scr[0]); f4acc(a1, scr[1]); f4acc(a2, scr[2]);
            const int base = grp * 388 + l6 * 6;
            A_bf32[base + 0] = bf16_pack2(a0.x, a0.y);
            A_bf32[base + 1] = bf16_pack2(a0.z, a0.w);
            A_bf32[base + 2] = bf16_pack2(a1.x, a1.y);
            A_bf32[base + 3] = bf16_pack2(a1.z, a1.w);
            A_bf32[base + 4] = bf16_pack2(a2.x, a2.y);
            A_bf32[base + 5] = bf16_pack2(a2.z, a2.w);
        }
    }
    __syncthreads();

    // ================= layer 1: MFMA (verified mapping) =================
    {
        const int wid  = tid >> 6;    // wave 0..7
        const int l    = tid & 63;
        const int lrow = l & 15;      // A row / D col
        const int lg   = l >> 4;      // k-group 0..3

        const int nb = wid * 48;      // this wave's 3 N-tiles: nb, nb+16, nb+32
        f32x4 acc[3] = {{0.f,0.f,0.f,0.f},{0.f,0.f,0.f,0.f},{0.f,0.f,0.f,0.f}};

        const unsigned int* abase = &A_bf32[lrow * 388 + lg * 4];
        const unsigned short* wp[3];
        #pragma unroll
        for (int j = 0; j < 3; ++j)
            wp[j] = W1T + (size_t)(nb + j * 16 + lrow) * 768 + lg * 8;

        for (int ks = 0; ks < 24; ++ks) {
            s16x8 af = *reinterpret_cast<const s16x8*>(abase + ks * 16);
            #pragma unroll
            for (int j = 0; j < 3; ++j) {
                s16x8 bf = *reinterpret_cast<const s16x8*>(wp[j] + ks * 32);
                acc[j] = __builtin_amdgcn_mfma_f32_16x16x32_bf16(af, bf, acc[j], 0, 0, 0);
            }
        }

        if (lg == 0) {   // rows 0..3 real; lg 1..3 hold pad rows 4-15
            #pragma unroll
            for (int j = 0; j < 3; ++j) {
                const int c = nb + j * 16 + lrow;
                const float bb = b1[c];
                #pragma unroll
                for (int r4 = 0; r4 < 4; ++r4) {
                    const float v = acc[j][r4] + bb;
                    X1[r4 * 384 + c] = v > 0.f ? v : 0.f;
                }
            }
        }
    }
    __syncthreads();

    // ================= layer 2: fp32 k-split =================
    const int c1 = lane;          // weight column 0..127
    const int kg = grp;           // k-slice group 0..3
    {
        float acc2[BM];
        #pragma unroll
        for (int r = 0; r < BM; ++r) acc2[r] = 0.f;

        const int k0 = kg * 96;
        for (int k = k0; k < k0 + 96; k += 4) {
            float4 x[BM];
            #pragma unroll
            for (int r = 0; r < BM; ++r)
                x[r] = *reinterpret_cast<const float4*>(&X1[r * 384 + k]);
            #pragma unroll
            for (int kk = 0; kk < 4; ++kk) {
                const float w = W2[(size_t)(k + kk) * 128 + c1];
                #pragma unroll
                for (int r = 0; r < BM; ++r)
                    acc2[r] = fmaf(f4get(x[r], kk), w, acc2[r]);
            }
        }
        #pragma unroll
        for (int r = 0; r < BM; ++r)
            P2[(kg * BM + r) * 128 + c1] = acc2[r];
    }
    __syncthreads();

    // ---- reduce partials -> X2 (bias + relu) ----
    {
        const int row = grp;      // 0..3
        const int col = c1;
        float s = b2[col];
        #pragma unroll
        for (int g = 0; g < 4; ++g)
            s += P2[(g * BM + row) * 128 + col];
        X2[row * 128 + col] = s > 0.f ? s : 0.f;
    }
    __syncthreads();

    // ---- layer 3: BM*2 = 8 outputs ----
    if (tid < BM * 2) {
        const int r = tid >> 1;
        const int c = tid & 1;
        float sacc = 0.f;
        #pragma unroll 8
        for (int k = 0; k < 128; ++k)
            sacc = fmaf(X2[r * 128 + k], W3[k * 2 + c], sacc);
        out[(row0 + r) * 2 + c] = sacc + b3[c];
    }
}

extern "C" void kernel_launch(void* const* d_in, const int* in_sizes, int n_in,
                              void* d_out, int out_size, void* d_ws, size_t ws_size,
                              hipStream_t stream) {
    const float* hidden = (const float*)d_in[0];
    const int*   seg    = (const int*)d_in[1];
    const float* W1     = (const float*)d_in[2];
    const float* b1     = (const float*)d_in[3];
    const float* W2     = (const float*)d_in[4];
    const float* b2     = (const float*)d_in[5];
    const float* W3     = (const float*)d_in[6];
    const float* b3     = (const float*)d_in[7];
    float* out = (float*)d_out;

    int* bounds = (int*)d_ws;                                     // 8.3 KB
    unsigned short* W1T = (unsigned short*)((char*)d_ws + 16384); // 576 KB

    prep_w1t_kernel<<<384, 768, 0, stream>>>(W1, W1T);
    bounds_kernel<<<BATCH, 192, 0, stream>>>(seg, bounds);
    fused_kernel<<<(BATCH * SMAX) / BM, 512, 0, stream>>>(
        hidden, bounds, W1T, b1, W2, b2, W3, b3, out);
}

// Round 19
// 70.169 us; speedup vs baseline: 1.1163x; 1.1163x over previous
//
#include <hip/hip_runtime.h>

#define BATCH 16
#define TOK   4096
#define DIM   768
#define SMAX  128
#define BM    8     // rows per MLP block

typedef float f32x4 __attribute__((ext_vector_type(4)));
typedef short s16x8 __attribute__((ext_vector_type(8)));

__device__ __forceinline__ int lower_bound_i(const int* __restrict__ a, int n, int v) {
    int lo = 0, hi = n;
    while (lo < hi) {
        int m = (lo + hi) >> 1;
        if (a[m] < v) lo = m + 1; else hi = m;
    }
    return lo;
}

__device__ __forceinline__ float f4get(const float4& v, int k) {
    switch (k) {
        case 0: return v.x;
        case 1: return v.y;
        case 2: return v.z;
        default: return v.w;
    }
}

__device__ __forceinline__ void f4acc(float4& a, const float4& v) {
    a.x += v.x; a.y += v.y; a.z += v.z; a.w += v.w;
}

// bf16 round-to-nearest-even (prep kernel, off hot path)
__device__ __forceinline__ unsigned short bf16_rne(float f) {
    unsigned int u = __float_as_uint(f);
    u += 0x7FFFu + ((u >> 16) & 1u);
    return (unsigned short)(u >> 16);
}

// pack two f32 -> bf16x2 (round-half-up)
__device__ __forceinline__ unsigned int bf16_pack2(float f0, float f1) {
    unsigned int u0 = __float_as_uint(f0) + 0x8000u;
    unsigned int u1 = __float_as_uint(f1) + 0x8000u;
    return (u0 >> 16) | (u1 & 0xFFFF0000u);
}

// Prep: W1 [768][384] f32 -> W1T [384][768] bf16 (RNE).
__global__ __launch_bounds__(768)
void prep_w1t_kernel(const float* __restrict__ W1, unsigned short* __restrict__ W1T) {
    const int c = blockIdx.x;     // 0..383
    const int k = threadIdx.x;    // 0..767
    W1T[c * 768 + k] = bf16_rne(W1[(size_t)k * 384 + c]);
}

// Kernel 0: precompute span boundaries (independent parallel searches).
__global__ __launch_bounds__(192)
void bounds_kernel(const int* __restrict__ seg, int* __restrict__ bounds) {
    const int b = blockIdx.x;
    const int s = threadIdx.x;
    if (s <= SMAX)
        bounds[b * (SMAX + 1) + s] = lower_bound_i(seg + b * TOK, TOK, s);
}

// Kernel A: segment sum, R3-proven fully-coalesced layout (thread = one
// float4 column), grid 2048 = 8 blocks/CU for max streaming TLP.
// Output packed bf16 (halves the sent round-trip; same quantization point
// as the fused variant -> absmax unchanged).
__global__ __launch_bounds__(192)
void segsum_bf16_kernel(const float* __restrict__ hidden,
                        const int* __restrict__ bounds,
                        unsigned int* __restrict__ sentb) {  // [B*SMAX][384] u32
    const int s = blockIdx.x;
    const int b = blockIdx.y;
    const int tid = threadIdx.x;

    const int lo = bounds[b * (SMAX + 1) + s];
    const int hi = bounds[b * (SMAX + 1) + s + 1];

    const float4* __restrict__ hp =
        reinterpret_cast<const float4*>(hidden + (size_t)b * TOK * DIM) + tid;

    float4 acc = make_float4(0.f, 0.f, 0.f, 0.f);
    int t = lo;

    for (; t + 16 <= hi; t += 16) {
        float4 v[16];
        #pragma unroll
        for (int u = 0; u < 16; ++u)
            v[u] = hp[(size_t)(t + u) * (DIM / 4)];
        #pragma unroll
        for (int u = 0; u < 16; ++u)
            f4acc(acc, v[u]);
    }
    for (; t + 4 <= hi; t += 4) {
        float4 v[4];
        #pragma unroll
        for (int u = 0; u < 4; ++u)
            v[u] = hp[(size_t)(t + u) * (DIM / 4)];
        #pragma unroll
        for (int u = 0; u < 4; ++u)
            f4acc(acc, v[u]);
    }
    for (; t < hi; ++t)
        f4acc(acc, hp[(size_t)t * (DIM / 4)]);

    // pack 4 floats -> 2 u32 of bf16x2; coalesced uint2 store
    uint2 pk;
    pk.x = bf16_pack2(acc.x, acc.y);
    pk.y = bf16_pack2(acc.z, acc.w);
    reinterpret_cast<uint2*>(sentb + (size_t)(b * SMAX + s) * 384)[tid] = pk;
}

// Kernel B: MLP head. BM=8 rows, 1024 thr, grid 256 (weights read once per
// block = minimal L2 stream). Stages bf16 sent rows into padded LDS A-tile
// [16][776] then R14-verified mfma_f32_16x16x32_bf16 layer1; fp32 layer2/3.
__global__ __launch_bounds__(1024)
void mlp_kernel(const unsigned int* __restrict__ sentb,
                const unsigned short* __restrict__ W1T, const float* __restrict__ b1,
                const float* __restrict__ W2, const float* __restrict__ b2,
                const float* __restrict__ W3, const float* __restrict__ b3,
                float* __restrict__ out) {
    __shared__ __align__(16) unsigned int A_bf32[16 * 388]; // 16 rows x 776 bf16 = 24.8 KB
    __shared__ __align__(16) float X1[BM * 384];            // 12 KB
    __shared__ __align__(16) float X2[BM * 128];            //  4 KB
    __shared__ __align__(16) float P2[8 * BM * 128];        // 32 KB

    const int tid  = threadIdx.x;
    const int row0 = blockIdx.x * BM;
    const int grp  = tid >> 7;    // 0..7
    const int lane = tid & 127;

    // stage A rows (bf16 u32 pairs) + zero pad rows 8-15
    {
        const unsigned int* src = sentb + (size_t)row0 * 384;
        #pragma unroll
        for (int i = 0; i < 3; ++i) {
            const int idx = tid + i * 1024;   // 0..3071
            const int row = idx / 384;
            const int col = idx - row * 384;
            A_bf32[row * 388 + col] = src[idx];
        }
        for (int i = tid; i < 8 * 388; i += 1024)
            A_bf32[8 * 388 + i] = 0u;
    }
    __syncthreads();

    // ---- layer 1: MFMA (R14-verified mapping) ----
    {
        const int wid  = tid >> 6;    // wave 0..15
        const int l    = tid & 63;
        const int lrow = l & 15;      // A row / D col
        const int lg   = l >> 4;      // k-group 0..3

        if (wid < 12) {
            const int n0 = wid * 32;
            const int n1 = n0 + 16;
            f32x4 acc0 = {0.f, 0.f, 0.f, 0.f};
            f32x4 acc1 = {0.f, 0.f, 0.f, 0.f};

            const unsigned int* abase = &A_bf32[lrow * 388 + lg * 4];
            const unsigned short* w0p = W1T + (size_t)(n0 + lrow) * 768 + lg * 8;
            const unsigned short* w1p = W1T + (size_t)(n1 + lrow) * 768 + lg * 8;

            for (int ks = 0; ks < 24; ++ks) {
                s16x8 af  = *reinterpret_cast<const s16x8*>(abase + ks * 16);
                s16x8 bf0 = *reinterpret_cast<const s16x8*>(w0p + ks * 32);
                s16x8 bf1 = *reinterpret_cast<const s16x8*>(w1p + ks * 32);
                acc0 = __builtin_amdgcn_mfma_f32_16x16x32_bf16(af, bf0, acc0, 0, 0, 0);
                acc1 = __builtin_amdgcn_mfma_f32_16x16x32_bf16(af, bf1, acc1, 0, 0, 0);
            }

            if (lg < 2) {   // rows 0..7 real; lg 2,3 hold pad rows 8-15
                const int c0  = n0 + lrow;
                const int c1c = n1 + lrow;
                const float bb0 = b1[c0];
                const float bb1 = b1[c1c];
                #pragma unroll
                for (int r4 = 0; r4 < 4; ++r4) {
                    const int row = lg * 4 + r4;
                    const float v0 = acc0[r4] + bb0;
                    const float v1 = acc1[r4] + bb1;
                    X1[row * 384 + c0]  = v0 > 0.f ? v0 : 0.f;
                    X1[row * 384 + c1c] = v1 > 0.f ? v1 : 0.f;
                }
            }
        }
    }
    __syncthreads();

    // ---- layer 2: fp32 k-split (R10-verified) ----
    const int c1 = lane;          // weight column within 128-group
    const int kg = grp;           // k-slice group 0..7
    {
        float acc2[BM];
        #pragma unroll
        for (int r = 0; r < BM; ++r) acc2[r] = 0.f;

        const int k0 = kg * 48;
        for (int k = k0; k < k0 + 48; k += 4) {
            float4 x[BM];
            #pragma unroll
            for (int r = 0; r < BM; ++r)
                x[r] = *reinterpret_cast<const float4*>(&X1[r * 384 + k]);
            #pragma unroll
            for (int kk = 0; kk < 4; ++kk) {
                const float w = W2[(size_t)(k + kk) * 128 + c1];
                #pragma unroll
                for (int r = 0; r < BM; ++r)
                    acc2[r] = fmaf(f4get(x[r], kk), w, acc2[r]);
            }
        }
        #pragma unroll
        for (int r = 0; r < BM; ++r)
            P2[(kg * BM + r) * 128 + c1] = acc2[r];
    }
    __syncthreads();

    // ---- reduce partials -> X2 (bias + relu) ----
    {
        const int row = grp;
        const int col = c1;
        float s = b2[col];
        #pragma unroll
        for (int g = 0; g < 8; ++g)
            s += P2[(g * BM + row) * 128 + col];
        X2[row * 128 + col] = s > 0.f ? s : 0.f;
    }
    __syncthreads();

    // ---- layer 3: 16 outputs ----
    if (tid < BM * 2) {
        const int r = tid >> 1;
        const int c = tid & 1;
        float sacc = 0.f;
        #pragma unroll 8
        for (int k = 0; k < 128; ++k)
            sacc = fmaf(X2[r * 128 + k], W3[k * 2 + c], sacc);
        out[(row0 + r) * 2 + c] = sacc + b3[c];
    }
}

extern "C" void kernel_launch(void* const* d_in, const int* in_sizes, int n_in,
                              void* d_out, int out_size, void* d_ws, size_t ws_size,
                              hipStream_t stream) {
    const float* hidden = (const float*)d_in[0];
    const int*   seg    = (const int*)d_in[1];
    const float* W1     = (const float*)d_in[2];
    const float* b1     = (const float*)d_in[3];
    const float* W2     = (const float*)d_in[4];
    const float* b2     = (const float*)d_in[5];
    const float* W3     = (const float*)d_in[6];
    const float* b3     = (const float*)d_in[7];
    float* out = (float*)d_out;

    int* bounds = (int*)d_ws;                                      // 8.3 KB
    unsigned short* W1T = (unsigned short*)((char*)d_ws + 16384);  // 576 KB
    unsigned int* sentb = (unsigned int*)((char*)d_ws + 16384 + 589824 + 1024); // 3 MB

    prep_w1t_kernel<<<384, 768, 0, stream>>>(W1, W1T);
    bounds_kernel<<<BATCH, 192, 0, stream>>>(seg, bounds);
    segsum_bf16_kernel<<<dim3(SMAX, BATCH), 192, 0, stream>>>(hidden, bounds, sentb);
    mlp_kernel<<<(BATCH * SMAX) / BM, 1024, 0, stream>>>(
        sentb, W1T, b1, W2, b2, W3, b3, out);
}